// Round 23
// baseline (217.307 us; speedup 1.0000x reference)
//
#include <hip/hip_runtime.h>
#include <cstdint>
#include <cstddef>

using f32x4 = __attribute__((ext_vector_type(4))) float;

#define TDIM 2048
#define HDIM 2048
#define IDIM 1408
#define NEXP 8
#define NKB1 16   // H/128
#define NKB2 11   // I/128
#define MAXM 4096 // T*TOPK
#define N8GUP 5767168   // gate_up elems/8 (= 11 * 524288)
#define N8DWN 2883584   // down elems/8    (= 5.5 * 524288)
#define PBLK  2048      // prep resident blocks
#define PSTR  (PBLK * 256)  // 524288 grid-stride

// ---- async global->LDS, 16B/lane. LDS dest: wave-uniform base + lane*16.
__device__ __forceinline__ void gll16(const void* g, void* l) {
  __builtin_amdgcn_global_load_lds(
      (__attribute__((address_space(1))) void*)(uintptr_t)g,
      (__attribute__((address_space(3))) void*)(uint32_t)(uintptr_t)l,
      16, 0, 0);
}

__device__ __forceinline__ f32x4 mfma_fp8(long a, long b, f32x4 c) {
  return __builtin_amdgcn_mfma_f32_16x16x32_fp8_fp8(a, b, c, 0, 0, 0);
}

// fp8 convert (RNE, pre-clamped like reference's clip).
__device__ __forceinline__ uint32_t f8_1(float q) {
  q = fminf(fmaxf(q, -448.f), 448.f);
  return (uint32_t)__builtin_amdgcn_cvt_pk_fp8_f32(q, q, 0, false) & 0xffu;
}

__device__ __forceinline__ float bf16_to_f32(uint32_t bits16) {
  union { uint32_t u; float f; } c;
  c.u = bits16 << 16;
  return c.f;
}

// ============ kernel -1: sniff weight storage dtype + zero cnt ============
__global__ void sniff_kernel(const uint16_t* __restrict__ a,
                             const uint16_t* __restrict__ b,
                             int* __restrict__ modes, int* __restrict__ cnt) {
  if (threadIdx.x < 8) cnt[threadIdx.x] = 0;
  if (threadIdx.x == 0) {
    unsigned acc = 0;
    for (int i = 0; i < 128; ++i) acc |= a[2 * i];
    modes[0] = (acc == 0) ? 1 : 0;   // 1 = f32 storage, 0 = bf16 storage
    acc = 0;
    for (int i = 0; i < 128; ++i) acc |= b[2 * i];
    modes[1] = (acc == 0) ? 1 : 0;
  }
}

// ============ kernel 0: FUSED prep, resident grid-stride (2048 blocks) ============
// Every thread: 11 gup-repack granules + 5/6 dwn granules + 2 quantx groups,
// grid-strided (m13 streaming pattern); route in blocks 0..15. Per-element
// math identical to R22. Independent iterations -> compiler pipelines loads.
__global__ __launch_bounds__(256) void prep_kernel(
    const void* __restrict__ gup, const void* __restrict__ dwn,
    uint8_t* __restrict__ gq, uint8_t* __restrict__ dq,
    const int* __restrict__ modes,
    const float* __restrict__ x,
    uint8_t* __restrict__ xq, float* __restrict__ xs,
    const void* __restrict__ idxraw,
    int* __restrict__ list, int* __restrict__ cnt) {
  const int tid = threadIdx.x;
  const int gid = blockIdx.x * 256 + tid;
  // ---- route (blocks 0..15; 4096 slots) ----
  if (blockIdx.x < 16) {
    const long long* p = (const long long*)idxraw;
    unsigned hi = 0;
#pragma unroll
    for (int j = 0; j < 16; ++j) hi |= (unsigned)((unsigned long long)p[j] >> 32);
    int e;
    if (hi == 0) {
      e = (int)p[gid];                     // int64 storage
    } else {
      long long v = p[gid >> 1];           // int32 storage
      e = (int)((gid & 1) ? (v >> 32) : (v & 0xffffffffLL));
    }
    e &= 7;
    const int pos = atomicAdd(&cnt[e], 1);
    list[e * MAXM + pos] = gid;
  }
  // ---- gate_up repack: 11 exact grid-stride iterations ----
  {
    const int m = modes[0];
    if (m == 1) {
      const f32x4* p = (const f32x4*)gup;
#pragma unroll 2
      for (size_t g = gid; g < N8GUP; g += PSTR) {
        const f32x4 a = p[2 * g], b = p[2 * g + 1];
        uint32_t lo = 0, hi = 0;
#pragma unroll
        for (int q = 0; q < 4; ++q) {
          lo |= f8_1(a[q]) << (8 * q);
          hi |= f8_1(b[q]) << (8 * q);
        }
        ((uint2*)gq)[g] = make_uint2(lo, hi);
      }
    } else {
      const uint4* p = (const uint4*)gup;
#pragma unroll 2
      for (size_t g = gid; g < N8GUP; g += PSTR) {
        const uint4 v = p[g];
        uint32_t lo = 0, hi = 0;
#pragma unroll
        for (int q = 0; q < 2; ++q) {
          uint32_t w0 = (&v.x)[q];
          uint32_t w1 = (&v.x)[q + 2];
          lo |= f8_1(bf16_to_f32(w0 & 0xffffu)) << (16 * q);
          lo |= f8_1(bf16_to_f32(w0 >> 16)) << (16 * q + 8);
          hi |= f8_1(bf16_to_f32(w1 & 0xffffu)) << (16 * q);
          hi |= f8_1(bf16_to_f32(w1 >> 16)) << (16 * q + 8);
        }
        ((uint2*)dq)[0] = ((uint2*)dq)[0];  // no-op guard (never taken path parity)
        ((uint2*)gq)[g] = make_uint2(lo, hi);
      }
    }
  }
  // ---- down repack: 5-6 grid-stride iterations ----
  {
    const int m = modes[1];
    if (m == 1) {
      const f32x4* p = (const f32x4*)dwn;
#pragma unroll 2
      for (size_t g = gid; g < N8DWN; g += PSTR) {
        const f32x4 a = p[2 * g], b = p[2 * g + 1];
        uint32_t lo = 0, hi = 0;
#pragma unroll
        for (int q = 0; q < 4; ++q) {
          lo |= f8_1(a[q]) << (8 * q);
          hi |= f8_1(b[q]) << (8 * q);
        }
        ((uint2*)dq)[g] = make_uint2(lo, hi);
      }
    } else {
      const uint4* p = (const uint4*)dwn;
#pragma unroll 2
      for (size_t g = gid; g < N8DWN; g += PSTR) {
        const uint4 v = p[g];
        uint32_t lo = 0, hi = 0;
#pragma unroll
        for (int q = 0; q < 2; ++q) {
          uint32_t w0 = (&v.x)[q];
          uint32_t w1 = (&v.x)[q + 2];
          lo |= f8_1(bf16_to_f32(w0 & 0xffffu)) << (16 * q);
          lo |= f8_1(bf16_to_f32(w0 >> 16)) << (16 * q + 8);
          hi |= f8_1(bf16_to_f32(w1 & 0xffffu)) << (16 * q);
          hi |= f8_1(bf16_to_f32(w1 >> 16)) << (16 * q + 8);
        }
        ((uint2*)dq)[g] = make_uint2(lo, hi);
      }
    }
  }
  // ---- quantx: 2 exact iterations (32768 groups / 16384 per sweep) ----
#pragma unroll
  for (int it = 0; it < 2; ++it) {
    const int gidq = blockIdx.x * 8 + (tid >> 5) + it * (PBLK * 8);
    const int l = tid & 31;
    const int r = gidq >> 4, kb = gidq & 15;
    const float* base = x + (size_t)r * HDIM + kb * 128 + l * 4;
    const f32x4 v = *(const f32x4*)base;
    float a = fmaxf(fmaxf(fabsf(v[0]), fabsf(v[1])), fmaxf(fabsf(v[2]), fabsf(v[3])));
#pragma unroll
    for (int d = 1; d < 32; d <<= 1) a = fmaxf(a, __shfl_xor(a, d));
    const float s = fmaxf(a, 1e-12f) / 448.f;
    uint32_t pk = 0;
#pragma unroll
    for (int j = 0; j < 4; ++j) pk |= f8_1(v[j] / s) << (8 * j);
    *(uint32_t*)(xq + (size_t)r * HDIM + kb * 128 + l * 4) = pk;
    if (l == 0) xs[r * 16 + kb] = s;
  }
}

// ============ kernel 3: gate_up GEMM + silu*up + h-quant (champion) ============
// 64x(128g+128u) tile, 256 thr (4 waves, 2M x 2N), BK=128. Grid (11,64,8).
// B double-buffered via gll16; A reg-staged into single LDS buf.
__global__ __launch_bounds__(256) void gemm1_kernel(
    const uint8_t* __restrict__ xq, const float* __restrict__ xs,
    const uint8_t* __restrict__ w, const float* __restrict__ wscl,
    const int* __restrict__ list, const int* __restrict__ cnt,
    uint8_t* __restrict__ hq, float* __restrict__ hs) {
  const int e = blockIdx.z, mt = blockIdx.y, nb = blockIdx.x;
  const int M = cnt[e];
  if (mt * 64 >= M) return;
  __shared__ __align__(16) uint8_t As[8192];
  __shared__ __align__(16) uint8_t Bg[2 * 16384];
  __shared__ __align__(16) uint8_t Bu[2 * 16384];
  __shared__ int slots[64];
  __shared__ __align__(16) float sxsAll[16][64];
  __shared__ __align__(16) float amx[128];
  const int tid = threadIdx.x, lane = tid & 63, wid = tid >> 6;
  const int wr = wid >> 1, wc = wid & 1;
  if (tid < 64) {
    int m = mt * 64 + tid;
    slots[tid] = list[e * MAXM + (m < M ? m : 0)];
  }
  __syncthreads();
  {
    const int r = tid >> 2, q = tid & 3;
    const int tok = slots[r] >> 1;
    f32x4 v = *(const f32x4*)(xs + (size_t)tok * 16 + q * 4);
    sxsAll[q * 4 + 0][r] = v[0];
    sxsAll[q * 4 + 1][r] = v[1];
    sxsAll[q * 4 + 2][r] = v[2];
    sxsAll[q * 4 + 3][r] = v[3];
  }
  const int s = tid >> 3;                           // 0..31
  const int cj0 = ((tid & 7) ^ (s & 7)) << 4;       // pre-swizzled source chunk
  const long tokA0 = slots[s] >> 1;
  const long tokA1 = slots[s + 32] >> 1;
  const uint8_t* pA0 = xq + tokA0 * HDIM + cj0;
  const uint8_t* pA1 = xq + tokA1 * HDIM + cj0;
  const size_t wb = (size_t)e * (2 * IDIM) * HDIM;
  const uint8_t* pG = w + wb + (size_t)(nb * 128 + s) * HDIM + cj0;
  const uint8_t* pU = w + wb + (size_t)(IDIM + nb * 128 + s) * HDIM + cj0;
  const float* wsg = wscl + (size_t)e * 352 + nb * 16;   // (E,22,16)
  const float* wsu = wsg + 176;
  f32x4 accg[2][4] = {};
  f32x4 accu[2][4] = {};
  const int kbyte = (lane >> 4) << 3;
#define STAGEB(d, kk) { const int ko_ = (kk) << 7; \
    _Pragma("unroll") \
    for (int k = 0; k < 4; ++k) { \
      gll16(pG + (size_t)(k * 32) * HDIM + ko_, Bg + (d) * 16384 + k * 4096 + tid * 16); \
      gll16(pU + (size_t)(k * 32) * HDIM + ko_, Bu + (d) * 16384 + k * 4096 + tid * 16); \
    } }
  f32x4 rA0 = *(const f32x4*)(pA0);
  f32x4 rA1 = *(const f32x4*)(pA1);
  STAGEB(0, 0)
  __syncthreads();
  int cur = 0;
  for (int kb = 0; kb < NKB1; ++kb) {
    *(f32x4*)(As + tid * 16) = rA0;
    *(f32x4*)(As + 4096 + tid * 16) = rA1;
    if (kb + 1 < NKB1) {
      STAGEB(cur ^ 1, kb + 1)
      const int ko = (kb + 1) << 7;
      rA0 = *(const f32x4*)(pA0 + ko);
      rA1 = *(const f32x4*)(pA1 + ko);
    }
    asm volatile("s_waitcnt lgkmcnt(0)" ::: "memory");
    __builtin_amdgcn_s_barrier();                        // B1: As(kb) visible
    const float swg = wsg[kb];
    const float swu = wsu[kb];
    const uint8_t* Bgb = Bg + cur * 16384;
    const uint8_t* Bub = Bu + cur * 16384;
    long af[2][4], bgf[4][4], buf_[4][4];
#pragma unroll
    for (int mi = 0; mi < 2; ++mi) {
      const int r = wr * 32 + mi * 16 + (lane & 15);
      const int xr = (r & 7) << 4;
      const uint8_t* bp = As + r * 128;
#pragma unroll
      for (int kc = 0; kc < 4; ++kc)
        af[mi][kc] = *(const long*)(bp + (((kc << 5) + kbyte) ^ xr));
    }
#pragma unroll
    for (int ni = 0; ni < 4; ++ni) {
      const int r = wc * 64 + ni * 16 + (lane & 15);
      const int xr = (r & 7) << 4;
      const uint8_t* bpg = Bgb + r * 128;
      const uint8_t* bpu = Bub + r * 128;
#pragma unroll
      for (int kc = 0; kc < 4; ++kc) {
        bgf[ni][kc] = *(const long*)(bpg + (((kc << 5) + kbyte) ^ xr));
        buf_[ni][kc] = *(const long*)(bpu + (((kc << 5) + kbyte) ^ xr));
      }
    }
    f32x4 sxg[2], sxu[2];
#pragma unroll
    for (int mi = 0; mi < 2; ++mi) {
      f32x4 sx = *(const f32x4*)(&sxsAll[kb][wr * 32 + mi * 16 + ((lane >> 4) << 2)]);
      sxg[mi] = sx * swg;
      sxu[mi] = sx * swu;
    }
    asm volatile("s_waitcnt lgkmcnt(0)" ::: "memory");
    __builtin_amdgcn_sched_barrier(0);
#pragma unroll
    for (int mi = 0; mi < 2; ++mi)
#pragma unroll
      for (int ni = 0; ni < 4; ++ni) {
        f32x4 pg = {0.f, 0.f, 0.f, 0.f};
        f32x4 pu = {0.f, 0.f, 0.f, 0.f};
#pragma unroll
        for (int kc = 0; kc < 4; ++kc) {
          pg = mfma_fp8(af[mi][kc], bgf[ni][kc], pg);
          pu = mfma_fp8(af[mi][kc], buf_[ni][kc], pu);
        }
#pragma unroll
        for (int j = 0; j < 4; ++j) {
          accg[mi][ni][j] += pg[j] * sxg[mi][j];
          accu[mi][ni][j] += pu[j] * sxu[mi][j];
        }
      }
    asm volatile("s_waitcnt vmcnt(0)" ::: "memory");
    __builtin_amdgcn_s_barrier();                      // B2
    cur ^= 1;
  }
#undef STAGEB
  f32x4 hv[2][4];
  f32x4 rmax[2];
#pragma unroll
  for (int mi = 0; mi < 2; ++mi) {
#pragma unroll
    for (int ni = 0; ni < 4; ++ni)
#pragma unroll
      for (int j = 0; j < 4; ++j) {
        float g = accg[mi][ni][j];
        float u = accu[mi][ni][j];
        float h = (g / (1.f + expf(-g))) * u;
        hv[mi][ni][j] = h;
        float ah = fabsf(h);
        rmax[mi][j] = (ni == 0) ? ah : fmaxf(rmax[mi][j], ah);
      }
#pragma unroll
    for (int d = 1; d < 16; d <<= 1)
#pragma unroll
      for (int j = 0; j < 4; ++j)
        rmax[mi][j] = fmaxf(rmax[mi][j], __shfl_xor(rmax[mi][j], d));
  }
  __syncthreads();
  if ((lane & 15) == 0) {
#pragma unroll
    for (int mi = 0; mi < 2; ++mi)
#pragma unroll
      for (int j = 0; j < 4; ++j) {
        int row = wr * 32 + mi * 16 + ((lane >> 4) << 2) + j;
        amx[row * 2 + wc] = rmax[mi][j];
      }
  }
  __syncthreads();
  const int Mrem = M - mt * 64;
#pragma unroll
  for (int mi = 0; mi < 2; ++mi)
#pragma unroll
    for (int j = 0; j < 4; ++j) {
      const int row = wr * 32 + mi * 16 + ((lane >> 4) << 2) + j;
      float am = fmaxf(amx[row * 2], amx[row * 2 + 1]);
      float sq = fmaxf(am, 1e-12f) / 448.f;
      if (row < Mrem) {
        const int slot = slots[row];
        uint8_t* hp = hq + (size_t)slot * IDIM + nb * 128 + wc * 64 + (lane & 15);
#pragma unroll
        for (int ni = 0; ni < 4; ++ni)
          hp[ni * 16] = (uint8_t)f8_1(hv[mi][ni][j] / sq);
        if (wc == 0 && (lane & 15) == 0) hs[slot * 16 + nb] = sq;  // stride 16
      }
    }
}

// ============ kernel 4: down GEMM -> per-slot tmp (champion) ============
// 64x128 tile, 256 thr (4 waves, 2M x 2N), BK=128, B dbuf + A reg-staged.
// Grid (16, 64, 8). LDS ~45.6KB -> 3 blocks/CU.
__global__ __launch_bounds__(256) void gemm2_kernel(
    const uint8_t* __restrict__ hq, const float* __restrict__ hs,
    const uint8_t* __restrict__ w, const float* __restrict__ wscl,
    const int* __restrict__ list, const int* __restrict__ cnt,
    const float* __restrict__ tkw, float* __restrict__ tmp) {
  const int e = blockIdx.z, mt = blockIdx.y, nt = blockIdx.x;
  const int M = cnt[e];
  if (mt * 64 >= M) return;
  __shared__ __align__(16) uint8_t As[8192];
  __shared__ __align__(16) uint8_t Bs[2 * 16384];
  __shared__ int slots[64];
  __shared__ float rwl[64];
  __shared__ __align__(16) float sxsAll[16][64];
  const int tid = threadIdx.x, lane = tid & 63, wid = tid >> 6;
  const int wr = wid >> 1, wc = wid & 1;
  if (tid < 64) {
    int m = mt * 64 + tid;
    int slot = list[e * MAXM + (m < M ? m : 0)];
    slots[tid] = slot;
    rwl[tid] = (m < M) ? tkw[slot] : 0.f;
  }
  __syncthreads();
  {
    const int r = tid >> 2, q = tid & 3;
    const float* ps = hs + (size_t)slots[r] * 16;
    f32x4 v = *(const f32x4*)(ps + q * 4);
    sxsAll[q * 4 + 0][r] = v[0];
    sxsAll[q * 4 + 1][r] = v[1];
    sxsAll[q * 4 + 2][r] = v[2];
    sxsAll[q * 4 + 3][r] = v[3];
  }
  const int s = tid >> 3;                           // 0..31
  const int cj0 = ((tid & 7) ^ (s & 7)) << 4;
  const long sA0 = slots[s];
  const long sA1 = slots[s + 32];
  const uint8_t* pA0 = hq + sA0 * IDIM + cj0;
  const uint8_t* pA1 = hq + sA1 * IDIM + cj0;
  const uint8_t* pB = w + (size_t)e * HDIM * IDIM + (size_t)(nt * 128 + s) * IDIM + cj0;
  const float* wsd = wscl + (size_t)e * 176 + nt * 11;  // (E,16,11)
  f32x4 acc[2][4] = {};
  const int kbyte = (lane >> 4) << 3;
#define STAGEB2(d, kk) { const int ko_ = (kk) << 7; \
    _Pragma("unroll") \
    for (int k = 0; k < 4; ++k) \
      gll16(pB + (size_t)(k * 32) * IDIM + ko_, Bs + (d) * 16384 + k * 4096 + tid * 16); }
  f32x4 rA0 = *(const f32x4*)(pA0);
  f32x4 rA1 = *(const f32x4*)(pA1);
  STAGEB2(0, 0)
  __syncthreads();
  int cur = 0;
  for (int kb = 0; kb < NKB2; ++kb) {
    *(f32x4*)(As + tid * 16) = rA0;
    *(f32x4*)(As + 4096 + tid * 16) = rA1;
    if (kb + 1 < NKB2) {
      STAGEB2(cur ^ 1, kb + 1)
      const int ko = (kb + 1) << 7;
      rA0 = *(const f32x4*)(pA0 + ko);
      rA1 = *(const f32x4*)(pA1 + ko);
    }
    asm volatile("s_waitcnt lgkmcnt(0)" ::: "memory");
    __builtin_amdgcn_s_barrier();                        // B1
    const float swd = wsd[kb];
    const uint8_t* Bb = Bs + cur * 16384;
    long af[2][4], bf[4][4];
#pragma unroll
    for (int mi = 0; mi < 2; ++mi) {
      const int r = wr * 32 + mi * 16 + (lane & 15);
      const int xr = (r & 7) << 4;
      const uint8_t* bp = As + r * 128;
#pragma unroll
      for (int kc = 0; kc < 4; ++kc)
        af[mi][kc] = *(const long*)(bp + (((kc << 5) + kbyte) ^ xr));
    }
#pragma unroll
    for (int ni = 0; ni < 4; ++ni) {
      const int r = wc * 64 + ni * 16 + (lane & 15);
      const int xr = (r & 7) << 4;
      const uint8_t* bp = Bb + r * 128;
#pragma unroll
      for (int kc = 0; kc < 4; ++kc)
        bf[ni][kc] = *(const long*)(bp + (((kc << 5) + kbyte) ^ xr));
    }
    f32x4 sxd[2];
#pragma unroll
    for (int mi = 0; mi < 2; ++mi) {
      f32x4 sx = *(const f32x4*)(&sxsAll[kb][wr * 32 + mi * 16 + ((lane >> 4) << 2)]);
      sxd[mi] = sx * swd;
    }
    asm volatile("s_waitcnt lgkmcnt(0)" ::: "memory");
    __builtin_amdgcn_sched_barrier(0);
#pragma unroll
    for (int mi = 0; mi < 2; ++mi)
#pragma unroll
      for (int ni = 0; ni < 4; ++ni) {
        f32x4 p = {0.f, 0.f, 0.f, 0.f};
#pragma unroll
        for (int kc = 0; kc < 4; ++kc) p = mfma_fp8(af[mi][kc], bf[ni][kc], p);
#pragma unroll
        for (int j = 0; j < 4; ++j) acc[mi][ni][j] += p[j] * sxd[mi][j];
      }
    asm volatile("s_waitcnt vmcnt(0)" ::: "memory");
    __builtin_amdgcn_s_barrier();                      // B2
    cur ^= 1;
  }
#undef STAGEB2
  const int Mrem = M - mt * 64;
#pragma unroll
  for (int mi = 0; mi < 2; ++mi)
#pragma unroll
    for (int j = 0; j < 4; ++j) {
      const int row = wr * 32 + mi * 16 + ((lane >> 4) << 2) + j;
      if (row < Mrem) {
        const int slot = slots[row];
        const float rw = rwl[row];
        float* op = tmp + (size_t)slot * HDIM + nt * 128 + wc * 64 + (lane & 15);
#pragma unroll
        for (int ni = 0; ni < 4; ++ni) op[ni * 16] = rw * acc[mi][ni][j];
      }
    }
}

// ============ kernel 5: out[t] = tmp[2t] + tmp[2t+1] ============
__global__ void reduce_kernel(const float* __restrict__ tmp, float* __restrict__ out) {
  const int i = blockIdx.x * 256 + threadIdx.x;
  const int t = i >> 9, c4 = i & 511;
  const f32x4 a = ((const f32x4*)tmp)[(size_t)(2 * t) * 512 + c4];
  const f32x4 c = ((const f32x4*)tmp)[(size_t)(2 * t) * 512 + 512 + c4];
  ((f32x4*)out)[i] = a + c;
}

extern "C" void kernel_launch(void* const* d_in, const int* in_sizes, int n_in,
                              void* d_out, int out_size, void* d_ws, size_t ws_size,
                              hipStream_t stream) {
  const float* hidden = (const float*)d_in[0];
  const void* topk_idx = d_in[1];
  const float* topk_w = (const float*)d_in[2];
  const void* gup_raw = d_in[3];   // fp8 values held as f32 or bf16 (sniffed)
  const float* gup_s = (const float*)d_in[4];
  const void* dwn_raw = d_in[5];
  const float* dwn_s = (const float*)d_in[6];
  float* out = (float*)d_out;
  uint8_t* ws = (uint8_t*)d_ws;
  // workspace layout (~79.7 MB); tmp (32MB) aliases gq (dead after gemm1)
  uint8_t* xq = ws;                           //  4,194,304
  float* xs = (float*)(ws + 4194304);         //    131,072
  uint8_t* hq = ws + 4325376;                 //  5,767,168
  float* hs = (float*)(ws + 10092544);        //    262,144 (4096 x 16 f32, padded)
  int* list = (int*)(ws + 10354688);          //    131,072
  int* cnt = (int*)(ws + 10485760);           //         64
  int* modes = (int*)(ws + 10485824);         //         64
  uint8_t* gq = ws + 10485888;                // 46,137,344 (gate_up fp8)
  float* tmp = (float*)gq;                    // 33,554,432 (aliases gq; gemm2/reduce only)
  uint8_t* dq = ws + 56623232;                // 23,068,672 (down fp8)
  (void)in_sizes; (void)n_in; (void)ws_size; (void)out_size;

  sniff_kernel<<<1, 64, 0, stream>>>((const uint16_t*)gup_raw, (const uint16_t*)dwn_raw, modes, cnt);
  prep_kernel<<<PBLK, 256, 0, stream>>>(
      gup_raw, dwn_raw, gq, dq, modes, hidden, xq, xs, topk_idx, list, cnt);
  gemm1_kernel<<<dim3(11, 64, 8), 256, 0, stream>>>(xq, xs, gq, gup_s, list, cnt, hq, hs);
  gemm2_kernel<<<dim3(16, 64, 8), 256, 0, stream>>>(hq, hs, dq, dwn_s, list, cnt, topk_w, tmp);
  reduce_kernel<<<4096, 256, 0, stream>>>(tmp, out);
}

// Round 24
// 209.710 us; speedup vs baseline: 1.0362x; 1.0362x over previous
//
#include <hip/hip_runtime.h>
#include <cstdint>
#include <cstddef>

using f32x4 = __attribute__((ext_vector_type(4))) float;

#define TDIM 2048
#define HDIM 2048
#define IDIM 1408
#define NEXP 8
#define NKB1 16   // H/128
#define NKB2 11   // I/128
#define MAXM 4096 // T*TOPK
#define N8GUP 5767168   // gate_up elems/8
#define N8DWN 2883584   // down elems/8
#define NBGUP 5632      // N8GUP/1024 (4 outputs/thread)
#define NBRPK 8448      // (N8GUP+N8DWN)/1024
#define NBQX  4096      // quantx blocks
#define NBRT  16        // route blocks

// ---- async global->LDS, 16B/lane. LDS dest: wave-uniform base + lane*16.
__device__ __forceinline__ void gll16(const void* g, void* l) {
  __builtin_amdgcn_global_load_lds(
      (__attribute__((address_space(1))) void*)(uintptr_t)g,
      (__attribute__((address_space(3))) void*)(uint32_t)(uintptr_t)l,
      16, 0, 0);
}

__device__ __forceinline__ f32x4 mfma_fp8(long a, long b, f32x4 c) {
  return __builtin_amdgcn_mfma_f32_16x16x32_fp8_fp8(a, b, c, 0, 0, 0);
}

// fp8 convert (RNE, pre-clamped like reference's clip).
__device__ __forceinline__ uint32_t f8_1(float q) {
  q = fminf(fmaxf(q, -448.f), 448.f);
  return (uint32_t)__builtin_amdgcn_cvt_pk_fp8_f32(q, q, 0, false) & 0xffu;
}

__device__ __forceinline__ float bf16_to_f32(uint32_t bits16) {
  union { uint32_t u; float f; } c;
  c.u = bits16 << 16;
  return c.f;
}

// ============ kernel -1: sniff weight storage dtype + zero cnt ============
__global__ void sniff_kernel(const uint16_t* __restrict__ a,
                             const uint16_t* __restrict__ b,
                             int* __restrict__ modes, int* __restrict__ cnt) {
  if (threadIdx.x < 8) cnt[threadIdx.x] = 0;
  if (threadIdx.x == 0) {
    unsigned acc = 0;
    for (int i = 0; i < 128; ++i) acc |= a[2 * i];
    modes[0] = (acc == 0) ? 1 : 0;   // 1 = f32 storage, 0 = bf16 storage
    acc = 0;
    for (int i = 0; i < 128; ++i) acc |= b[2 * i];
    modes[1] = (acc == 0) ? 1 : 0;
  }
}

// ============ kernel 0: FUSED prep — repack both weights + quantx + route ============
// Repack: 4 uint2 outputs (32 fp8) per thread. Blocks [0,NBGUP)=gate_up,
// [NBGUP,NBRPK)=down, then quantx, then route (cnt pre-zeroed by sniff).
__global__ void prep_kernel(const void* __restrict__ gup, const void* __restrict__ dwn,
                            uint8_t* __restrict__ gq, uint8_t* __restrict__ dq,
                            const int* __restrict__ modes,
                            const float* __restrict__ x,
                            uint8_t* __restrict__ xq, float* __restrict__ xs,
                            const void* __restrict__ idxraw,
                            int* __restrict__ list, int* __restrict__ cnt) {
  const int bid = blockIdx.x;
  if (bid < NBRPK) {
    const void* in;
    uint8_t* out;
    int midx, base;
    if (bid < NBGUP) { in = gup; out = gq; midx = 0; base = bid * 1024 + threadIdx.x; }
    else { in = dwn; out = dq; midx = 1; base = (bid - NBGUP) * 1024 + threadIdx.x; }
    const int m = modes[midx];
    uint32_t pk[4][2];
    if (m == 1) {            // f32 storage: 8 float4 loads in flight
      f32x4 va[8];
      const f32x4* p = (const f32x4*)in;
#pragma unroll
      for (int j = 0; j < 4; ++j) {
        const size_t o = 2 * (size_t)(base + j * 256);
        va[2 * j]     = p[o];
        va[2 * j + 1] = p[o + 1];
      }
#pragma unroll
      for (int j = 0; j < 8; ++j) {
        uint32_t v = 0;
#pragma unroll
        for (int q = 0; q < 4; ++q) v |= f8_1(va[j][q]) << (8 * q);
        pk[j >> 1][j & 1] = v;
      }
    } else {                 // bf16 storage: 4 uint4 loads in flight
      uint4 vb[4];
      const uint4* p = (const uint4*)in;
#pragma unroll
      for (int j = 0; j < 4; ++j) vb[j] = p[base + j * 256];
#pragma unroll
      for (int j = 0; j < 4; ++j) {
        uint32_t lo = 0, hi = 0;
#pragma unroll
        for (int q = 0; q < 2; ++q) {
          uint32_t w0 = (&vb[j].x)[q];
          uint32_t w1 = (&vb[j].x)[q + 2];
          lo |= f8_1(bf16_to_f32(w0 & 0xffffu)) << (16 * q);
          lo |= f8_1(bf16_to_f32(w0 >> 16)) << (16 * q + 8);
          hi |= f8_1(bf16_to_f32(w1 & 0xffffu)) << (16 * q);
          hi |= f8_1(bf16_to_f32(w1 >> 16)) << (16 * q + 8);
        }
        pk[j][0] = lo;
        pk[j][1] = hi;
      }
    }
#pragma unroll
    for (int j = 0; j < 4; ++j)
      ((uint2*)out)[base + j * 256] = make_uint2(pk[j][0], pk[j][1]);
  } else if (bid < NBRPK + NBQX) {
    // ---- quantx: one 32-lane group per (row, 128-col) quant block ----
    const int gid = (bid - NBRPK) * 8 + (threadIdx.x >> 5);
    const int l = threadIdx.x & 31;
    const int r = gid >> 4, kb = gid & 15;
    const float* base = x + (size_t)r * HDIM + kb * 128 + l * 4;
    const f32x4 v = *(const f32x4*)base;
    float a = fmaxf(fmaxf(fabsf(v[0]), fabsf(v[1])), fmaxf(fabsf(v[2]), fabsf(v[3])));
#pragma unroll
    for (int d = 1; d < 32; d <<= 1) a = fmaxf(a, __shfl_xor(a, d));
    const float s = fmaxf(a, 1e-12f) / 448.f;
    uint32_t pk = 0;
#pragma unroll
    for (int j = 0; j < 4; ++j) pk |= f8_1(v[j] / s) << (8 * j);
    *(uint32_t*)(xq + (size_t)r * HDIM + kb * 128 + l * 4) = pk;
    if (l == 0) xs[r * 16 + kb] = s;
  } else {
    // ---- route: slot = t*2+k -> per-expert lists (cnt zeroed by sniff) ----
    const long long* p = (const long long*)idxraw;
    unsigned hi = 0;
#pragma unroll
    for (int j = 0; j < 16; ++j) hi |= (unsigned)((unsigned long long)p[j] >> 32);
    const int i = (bid - NBRPK - NBQX) * 256 + threadIdx.x;
    int e;
    if (hi == 0) {
      e = (int)p[i];                       // int64 storage
    } else {
      long long v = p[i >> 1];             // int32 storage
      e = (int)((i & 1) ? (v >> 32) : (v & 0xffffffffLL));
    }
    e &= 7;
    const int pos = atomicAdd(&cnt[e], 1);
    list[e * MAXM + pos] = i;
  }
}

// ============ kernel 3: gate_up GEMM + silu*up + h-quant (champion) ============
// 64x(128g+128u) tile, 256 thr (4 waves, 2M x 2N), BK=128. Grid (11,64,8).
// B double-buffered via gll16; A reg-staged into single LDS buf.
__global__ __launch_bounds__(256) void gemm1_kernel(
    const uint8_t* __restrict__ xq, const float* __restrict__ xs,
    const uint8_t* __restrict__ w, const float* __restrict__ wscl,
    const int* __restrict__ list, const int* __restrict__ cnt,
    uint8_t* __restrict__ hq, float* __restrict__ hs) {
  const int e = blockIdx.z, mt = blockIdx.y, nb = blockIdx.x;
  const int M = cnt[e];
  if (mt * 64 >= M) return;
  __shared__ __align__(16) uint8_t As[8192];
  __shared__ __align__(16) uint8_t Bg[2 * 16384];
  __shared__ __align__(16) uint8_t Bu[2 * 16384];
  __shared__ int slots[64];
  __shared__ __align__(16) float sxsAll[16][64];
  __shared__ __align__(16) float amx[128];
  const int tid = threadIdx.x, lane = tid & 63, wid = tid >> 6;
  const int wr = wid >> 1, wc = wid & 1;
  if (tid < 64) {
    int m = mt * 64 + tid;
    slots[tid] = list[e * MAXM + (m < M ? m : 0)];
  }
  __syncthreads();
  {
    const int r = tid >> 2, q = tid & 3;
    const int tok = slots[r] >> 1;
    f32x4 v = *(const f32x4*)(xs + (size_t)tok * 16 + q * 4);
    sxsAll[q * 4 + 0][r] = v[0];
    sxsAll[q * 4 + 1][r] = v[1];
    sxsAll[q * 4 + 2][r] = v[2];
    sxsAll[q * 4 + 3][r] = v[3];
  }
  const int s = tid >> 3;                           // 0..31
  const int cj0 = ((tid & 7) ^ (s & 7)) << 4;       // pre-swizzled source chunk
  const long tokA0 = slots[s] >> 1;
  const long tokA1 = slots[s + 32] >> 1;
  const uint8_t* pA0 = xq + tokA0 * HDIM + cj0;
  const uint8_t* pA1 = xq + tokA1 * HDIM + cj0;
  const size_t wb = (size_t)e * (2 * IDIM) * HDIM;
  const uint8_t* pG = w + wb + (size_t)(nb * 128 + s) * HDIM + cj0;
  const uint8_t* pU = w + wb + (size_t)(IDIM + nb * 128 + s) * HDIM + cj0;
  const float* wsg = wscl + (size_t)e * 352 + nb * 16;   // (E,22,16)
  const float* wsu = wsg + 176;
  f32x4 accg[2][4] = {};
  f32x4 accu[2][4] = {};
  const int kbyte = (lane >> 4) << 3;
#define STAGEB(d, kk) { const int ko_ = (kk) << 7; \
    _Pragma("unroll") \
    for (int k = 0; k < 4; ++k) { \
      gll16(pG + (size_t)(k * 32) * HDIM + ko_, Bg + (d) * 16384 + k * 4096 + tid * 16); \
      gll16(pU + (size_t)(k * 32) * HDIM + ko_, Bu + (d) * 16384 + k * 4096 + tid * 16); \
    } }
  f32x4 rA0 = *(const f32x4*)(pA0);
  f32x4 rA1 = *(const f32x4*)(pA1);
  STAGEB(0, 0)
  __syncthreads();
  int cur = 0;
  for (int kb = 0; kb < NKB1; ++kb) {
    *(f32x4*)(As + tid * 16) = rA0;
    *(f32x4*)(As + 4096 + tid * 16) = rA1;
    if (kb + 1 < NKB1) {
      STAGEB(cur ^ 1, kb + 1)
      const int ko = (kb + 1) << 7;
      rA0 = *(const f32x4*)(pA0 + ko);
      rA1 = *(const f32x4*)(pA1 + ko);
    }
    asm volatile("s_waitcnt lgkmcnt(0)" ::: "memory");
    __builtin_amdgcn_s_barrier();                        // B1: As(kb) visible
    const float swg = wsg[kb];
    const float swu = wsu[kb];
    const uint8_t* Bgb = Bg + cur * 16384;
    const uint8_t* Bub = Bu + cur * 16384;
    long af[2][4], bgf[4][4], buf_[4][4];
#pragma unroll
    for (int mi = 0; mi < 2; ++mi) {
      const int r = wr * 32 + mi * 16 + (lane & 15);
      const int xr = (r & 7) << 4;
      const uint8_t* bp = As + r * 128;
#pragma unroll
      for (int kc = 0; kc < 4; ++kc)
        af[mi][kc] = *(const long*)(bp + (((kc << 5) + kbyte) ^ xr));
    }
#pragma unroll
    for (int ni = 0; ni < 4; ++ni) {
      const int r = wc * 64 + ni * 16 + (lane & 15);
      const int xr = (r & 7) << 4;
      const uint8_t* bpg = Bgb + r * 128;
      const uint8_t* bpu = Bub + r * 128;
#pragma unroll
      for (int kc = 0; kc < 4; ++kc) {
        bgf[ni][kc] = *(const long*)(bpg + (((kc << 5) + kbyte) ^ xr));
        buf_[ni][kc] = *(const long*)(bpu + (((kc << 5) + kbyte) ^ xr));
      }
    }
    f32x4 sxg[2], sxu[2];
#pragma unroll
    for (int mi = 0; mi < 2; ++mi) {
      f32x4 sx = *(const f32x4*)(&sxsAll[kb][wr * 32 + mi * 16 + ((lane >> 4) << 2)]);
      sxg[mi] = sx * swg;
      sxu[mi] = sx * swu;
    }
    asm volatile("s_waitcnt lgkmcnt(0)" ::: "memory");
    __builtin_amdgcn_sched_barrier(0);
#pragma unroll
    for (int mi = 0; mi < 2; ++mi)
#pragma unroll
      for (int ni = 0; ni < 4; ++ni) {
        f32x4 pg = {0.f, 0.f, 0.f, 0.f};
        f32x4 pu = {0.f, 0.f, 0.f, 0.f};
#pragma unroll
        for (int kc = 0; kc < 4; ++kc) {
          pg = mfma_fp8(af[mi][kc], bgf[ni][kc], pg);
          pu = mfma_fp8(af[mi][kc], buf_[ni][kc], pu);
        }
#pragma unroll
        for (int j = 0; j < 4; ++j) {
          accg[mi][ni][j] += pg[j] * sxg[mi][j];
          accu[mi][ni][j] += pu[j] * sxu[mi][j];
        }
      }
    asm volatile("s_waitcnt vmcnt(0)" ::: "memory");
    __builtin_amdgcn_s_barrier();                      // B2
    cur ^= 1;
  }
#undef STAGEB
  f32x4 hv[2][4];
  f32x4 rmax[2];
#pragma unroll
  for (int mi = 0; mi < 2; ++mi) {
#pragma unroll
    for (int ni = 0; ni < 4; ++ni)
#pragma unroll
      for (int j = 0; j < 4; ++j) {
        float g = accg[mi][ni][j];
        float u = accu[mi][ni][j];
        float h = (g / (1.f + expf(-g))) * u;
        hv[mi][ni][j] = h;
        float ah = fabsf(h);
        rmax[mi][j] = (ni == 0) ? ah : fmaxf(rmax[mi][j], ah);
      }
#pragma unroll
    for (int d = 1; d < 16; d <<= 1)
#pragma unroll
      for (int j = 0; j < 4; ++j)
        rmax[mi][j] = fmaxf(rmax[mi][j], __shfl_xor(rmax[mi][j], d));
  }
  __syncthreads();
  if ((lane & 15) == 0) {
#pragma unroll
    for (int mi = 0; mi < 2; ++mi)
#pragma unroll
      for (int j = 0; j < 4; ++j) {
        int row = wr * 32 + mi * 16 + ((lane >> 4) << 2) + j;
        amx[row * 2 + wc] = rmax[mi][j];
      }
  }
  __syncthreads();
  const int Mrem = M - mt * 64;
#pragma unroll
  for (int mi = 0; mi < 2; ++mi)
#pragma unroll
    for (int j = 0; j < 4; ++j) {
      const int row = wr * 32 + mi * 16 + ((lane >> 4) << 2) + j;
      float am = fmaxf(amx[row * 2], amx[row * 2 + 1]);
      float sq = fmaxf(am, 1e-12f) / 448.f;
      if (row < Mrem) {
        const int slot = slots[row];
        uint8_t* hp = hq + (size_t)slot * IDIM + nb * 128 + wc * 64 + (lane & 15);
#pragma unroll
        for (int ni = 0; ni < 4; ++ni)
          hp[ni * 16] = (uint8_t)f8_1(hv[mi][ni][j] / sq);
        if (wc == 0 && (lane & 15) == 0) hs[slot * 16 + nb] = sq;  // stride 16
      }
    }
}

// ============ kernel 4: down GEMM -> per-slot tmp (champion) ============
// 64x128 tile, 256 thr (4 waves, 2M x 2N), BK=128, B dbuf + A reg-staged.
// Grid (16, 64, 8). LDS ~45.6KB -> 3 blocks/CU.
__global__ __launch_bounds__(256) void gemm2_kernel(
    const uint8_t* __restrict__ hq, const float* __restrict__ hs,
    const uint8_t* __restrict__ w, const float* __restrict__ wscl,
    const int* __restrict__ list, const int* __restrict__ cnt,
    const float* __restrict__ tkw, float* __restrict__ tmp) {
  const int e = blockIdx.z, mt = blockIdx.y, nt = blockIdx.x;
  const int M = cnt[e];
  if (mt * 64 >= M) return;
  __shared__ __align__(16) uint8_t As[8192];
  __shared__ __align__(16) uint8_t Bs[2 * 16384];
  __shared__ int slots[64];
  __shared__ float rwl[64];
  __shared__ __align__(16) float sxsAll[16][64];
  const int tid = threadIdx.x, lane = tid & 63, wid = tid >> 6;
  const int wr = wid >> 1, wc = wid & 1;
  if (tid < 64) {
    int m = mt * 64 + tid;
    int slot = list[e * MAXM + (m < M ? m : 0)];
    slots[tid] = slot;
    rwl[tid] = (m < M) ? tkw[slot] : 0.f;
  }
  __syncthreads();
  {
    const int r = tid >> 2, q = tid & 3;
    const float* ps = hs + (size_t)slots[r] * 16;
    f32x4 v = *(const f32x4*)(ps + q * 4);
    sxsAll[q * 4 + 0][r] = v[0];
    sxsAll[q * 4 + 1][r] = v[1];
    sxsAll[q * 4 + 2][r] = v[2];
    sxsAll[q * 4 + 3][r] = v[3];
  }
  const int s = tid >> 3;                           // 0..31
  const int cj0 = ((tid & 7) ^ (s & 7)) << 4;
  const long sA0 = slots[s];
  const long sA1 = slots[s + 32];
  const uint8_t* pA0 = hq + sA0 * IDIM + cj0;
  const uint8_t* pA1 = hq + sA1 * IDIM + cj0;
  const uint8_t* pB = w + (size_t)e * HDIM * IDIM + (size_t)(nt * 128 + s) * IDIM + cj0;
  const float* wsd = wscl + (size_t)e * 176 + nt * 11;  // (E,16,11)
  f32x4 acc[2][4] = {};
  const int kbyte = (lane >> 4) << 3;
#define STAGEB2(d, kk) { const int ko_ = (kk) << 7; \
    _Pragma("unroll") \
    for (int k = 0; k < 4; ++k) \
      gll16(pB + (size_t)(k * 32) * IDIM + ko_, Bs + (d) * 16384 + k * 4096 + tid * 16); }
  f32x4 rA0 = *(const f32x4*)(pA0);
  f32x4 rA1 = *(const f32x4*)(pA1);
  STAGEB2(0, 0)
  __syncthreads();
  int cur = 0;
  for (int kb = 0; kb < NKB2; ++kb) {
    *(f32x4*)(As + tid * 16) = rA0;
    *(f32x4*)(As + 4096 + tid * 16) = rA1;
    if (kb + 1 < NKB2) {
      STAGEB2(cur ^ 1, kb + 1)
      const int ko = (kb + 1) << 7;
      rA0 = *(const f32x4*)(pA0 + ko);
      rA1 = *(const f32x4*)(pA1 + ko);
    }
    asm volatile("s_waitcnt lgkmcnt(0)" ::: "memory");
    __builtin_amdgcn_s_barrier();                        // B1
    const float swd = wsd[kb];
    const uint8_t* Bb = Bs + cur * 16384;
    long af[2][4], bf[4][4];
#pragma unroll
    for (int mi = 0; mi < 2; ++mi) {
      const int r = wr * 32 + mi * 16 + (lane & 15);
      const int xr = (r & 7) << 4;
      const uint8_t* bp = As + r * 128;
#pragma unroll
      for (int kc = 0; kc < 4; ++kc)
        af[mi][kc] = *(const long*)(bp + (((kc << 5) + kbyte) ^ xr));
    }
#pragma unroll
    for (int ni = 0; ni < 4; ++ni) {
      const int r = wc * 64 + ni * 16 + (lane & 15);
      const int xr = (r & 7) << 4;
      const uint8_t* bp = Bb + r * 128;
#pragma unroll
      for (int kc = 0; kc < 4; ++kc)
        bf[ni][kc] = *(const long*)(bp + (((kc << 5) + kbyte) ^ xr));
    }
    f32x4 sxd[2];
#pragma unroll
    for (int mi = 0; mi < 2; ++mi) {
      f32x4 sx = *(const f32x4*)(&sxsAll[kb][wr * 32 + mi * 16 + ((lane >> 4) << 2)]);
      sxd[mi] = sx * swd;
    }
    asm volatile("s_waitcnt lgkmcnt(0)" ::: "memory");
    __builtin_amdgcn_sched_barrier(0);
#pragma unroll
    for (int mi = 0; mi < 2; ++mi)
#pragma unroll
      for (int ni = 0; ni < 4; ++ni) {
        f32x4 p = {0.f, 0.f, 0.f, 0.f};
#pragma unroll
        for (int kc = 0; kc < 4; ++kc) p = mfma_fp8(af[mi][kc], bf[ni][kc], p);
#pragma unroll
        for (int j = 0; j < 4; ++j) acc[mi][ni][j] += p[j] * sxd[mi][j];
      }
    asm volatile("s_waitcnt vmcnt(0)" ::: "memory");
    __builtin_amdgcn_s_barrier();                      // B2
    cur ^= 1;
  }
#undef STAGEB2
  const int Mrem = M - mt * 64;
#pragma unroll
  for (int mi = 0; mi < 2; ++mi)
#pragma unroll
    for (int j = 0; j < 4; ++j) {
      const int row = wr * 32 + mi * 16 + ((lane >> 4) << 2) + j;
      if (row < Mrem) {
        const int slot = slots[row];
        const float rw = rwl[row];
        float* op = tmp + (size_t)slot * HDIM + nt * 128 + wc * 64 + (lane & 15);
#pragma unroll
        for (int ni = 0; ni < 4; ++ni) op[ni * 16] = rw * acc[mi][ni][j];
      }
    }
}

// ============ kernel 5: out[t] = tmp[2t] + tmp[2t+1] ============
__global__ void reduce_kernel(const float* __restrict__ tmp, float* __restrict__ out) {
  const int i = blockIdx.x * 256 + threadIdx.x;
  const int t = i >> 9, c4 = i & 511;
  const f32x4 a = ((const f32x4*)tmp)[(size_t)(2 * t) * 512 + c4];
  const f32x4 c = ((const f32x4*)tmp)[(size_t)(2 * t) * 512 + 512 + c4];
  ((f32x4*)out)[i] = a + c;
}

extern "C" void kernel_launch(void* const* d_in, const int* in_sizes, int n_in,
                              void* d_out, int out_size, void* d_ws, size_t ws_size,
                              hipStream_t stream) {
  const float* hidden = (const float*)d_in[0];
  const void* topk_idx = d_in[1];
  const float* topk_w = (const float*)d_in[2];
  const void* gup_raw = d_in[3];   // fp8 values held as f32 or bf16 (sniffed)
  const float* gup_s = (const float*)d_in[4];
  const void* dwn_raw = d_in[5];
  const float* dwn_s = (const float*)d_in[6];
  float* out = (float*)d_out;
  uint8_t* ws = (uint8_t*)d_ws;
  // workspace layout (~79.7 MB); tmp (32MB) aliases gq (dead after gemm1)
  uint8_t* xq = ws;                           //  4,194,304
  float* xs = (float*)(ws + 4194304);         //    131,072
  uint8_t* hq = ws + 4325376;                 //  5,767,168
  float* hs = (float*)(ws + 10092544);        //    262,144 (4096 x 16 f32, padded)
  int* list = (int*)(ws + 10354688);          //    131,072
  int* cnt = (int*)(ws + 10485760);           //         64
  int* modes = (int*)(ws + 10485824);         //         64
  uint8_t* gq = ws + 10485888;                // 46,137,344 (gate_up fp8)
  float* tmp = (float*)gq;                    // 33,554,432 (aliases gq; gemm2/reduce only)
  uint8_t* dq = ws + 56623232;                // 23,068,672 (down fp8)
  (void)in_sizes; (void)n_in; (void)ws_size; (void)out_size;

  sniff_kernel<<<1, 64, 0, stream>>>((const uint16_t*)gup_raw, (const uint16_t*)dwn_raw, modes, cnt);
  prep_kernel<<<NBRPK + NBQX + NBRT, 256, 0, stream>>>(
      gup_raw, dwn_raw, gq, dq, modes, hidden, xq, xs, topk_idx, list, cnt);
  gemm1_kernel<<<dim3(11, 64, 8), 256, 0, stream>>>(xq, xs, gq, gup_s, list, cnt, hq, hs);
  gemm2_kernel<<<dim3(16, 64, 8), 256, 0, stream>>>(hq, hs, dq, dwn_s, list, cnt, topk_w, tmp);
  reduce_kernel<<<4096, 256, 0, stream>>>(tmp, out);
}